// Round 7
// baseline (302.686 us; speedup 1.0000x reference)
//
#include <hip/hip_runtime.h>

// SSKernelNPLR, 2-kernel pipeline. H=256, N=32 (M=64 conj-extended), R=1, L=8192.
// K1 ssk_S (grid 512, 512 thr, 2 waves/SIMD): register-fused contour.
//    Thread owns node j; loop1 computes the folded G-factors (sx,sy,dx,dy) for
//    all 32 conj-state-pairs ONCE into 128 VGPRs while accumulating a_j, b_j
//    locally; q_j = z a/(1+b); loop2 consumes the registered folds for
//    S_m += q-fold. 4 nodes/thread, S-partials reduced by a 6-level in-register
//    wave butterfly (lane l ends with component l) + LDS cross-wave -> ws.
// K2 ssk_B (grid 256, 1024 thr): per-head algebra redo + combine S halves +
//    z=-1 node -> C~ -> v-vectors; Cauchy at z_j = 2i tan(pi j/L) + Woodbury
//    + (1+iT); real-irfft packing; 6-stage radix-4 Stockham inverse FFT -> out.

#define HH 256
#define NN 32
#define MF 4096

typedef float2 c32;

__device__ __forceinline__ c32 cmul(c32 a, c32 b){ return make_float2(a.x*b.x - a.y*b.y, a.x*b.y + a.y*b.x); }
__device__ __forceinline__ c32 cadd(c32 a, c32 b){ return make_float2(a.x+b.x, a.y+b.y); }
__device__ __forceinline__ c32 csub(c32 a, c32 b){ return make_float2(a.x-b.x, a.y-b.y); }
__device__ __forceinline__ c32 cconjf(c32 a){ return make_float2(a.x, -a.y); }
__device__ __forceinline__ float frcp(float x){ return __builtin_amdgcn_rcpf(x); }

// ---------------- K1: register-fused contour -> S partials ----------------
__global__ __launch_bounds__(512, 2)
void ssk_S(const float* __restrict__ log_dt, const float* __restrict__ invwr,
           const float* __restrict__ wim, const float* __restrict__ Pin,
           const float* __restrict__ Cin, float* __restrict__ Sws)
{
  __shared__ __align__(16) float4 ta_s[32];   // (d.x, d.y, pc.x, pc.y)
  __shared__ c32 pu_s[32];
  __shared__ float red[8*64];
  const int bid = blockIdx.x;
  const int h = bid >> 1;
  const int base = (bid & 1) << 11;           // 0 or 2048
  const int tid = threadIdx.x;

  // ---- A1: per-head algebra (wave 0; m = tid, conj half for m>=32) ----
  if (tid < 64) {
    const int n = tid & 31;
    const bool cj = tid >= 32;
    const float dt = expf(log_dt[h]);
    float wr = -expf(invwr[h*NN + n]);
    float wi = wim[h*NN + n];
    if (cj) wi = -wi;
    const float tdt = 2.0f / dt;
    float dr = tdt - wr, di = -wi;
    float invd = 1.0f / (dr*dr + di*di);
    c32 D = make_float2(dr*invd, -di*invd);   // 1/(2/dt - w)
    c32 E = make_float2(tdt + wr, wi);        // 2/dt + w
    c32 Pf = make_float2(Pin[(h*NN+n)*2], Pin[(h*NN+n)*2+1]);
    if (cj) Pf.y = -Pf.y;
    c32 Cf = make_float2(Cin[(h*NN+n)*2], Cin[(h*NN+n)*2+1]);
    if (cj) Cf.y = -Cf.y;
    float rm = (Pf.x*Pf.x + Pf.y*Pf.y) * D.x; // Rm = 1 + sum |Pf|^2 Re(D)
    #pragma unroll
    for (int off = 32; off >= 1; off >>= 1) rm += __shfl_xor(rm, off, 64);
    rm += 1.0f;
    c32 Rc = cmul(cconjf(Pf), D);
    float invrm = 1.0f / rm;
    Rc.x *= invrm; Rc.y *= invrm;
    c32 RP = cmul(Rc, Pf);
    #pragma unroll
    for (int off = 32; off >= 1; off >>= 1) {
      RP.x += __shfl_xor(RP.x, off, 64);
      RP.y += __shfl_xor(RP.y, off, 64);
    }
    c32 Q2 = cconjf(Pf);
    c32 s  = csub(cmul(Rc, E), cmul(RP, Q2));
    c32 u  = cadd(Q2, s);                     // dA = diag(dd) - pp u^T
    c32 dd = cmul(D, E);
    c32 pp = cmul(D, Pf);
    c32 pc = cmul(pp, Cf);
    c32 pu = cmul(pp, u);
    if (tid < 32) {
      ta_s[tid] = make_float4(dd.x, dd.y, pc.x, pc.y);
      pu_s[tid] = pu;
    }
  }
  __syncthreads();

  // ---- fused A2+A3: 4 nodes/thread ----
  float sAx[32], sAy[32];
  #pragma unroll
  for (int m = 0; m < 32; m++) { sAx[m] = 0.0f; sAy[m] = 0.0f; }

  for (int it = 0; it < 4; it++) {
    const int j = base + (it << 9) + tid;     // node index 0..4095
    float rev = (float)j * (1.0f/8192.0f);
    float zx = __builtin_amdgcn_cosf(rev);
    float zy = __builtin_amdgcn_sinf(rev);

    float fsx[32], fsy[32], fdx[32], fdy[32];
    float ax = 0.0f, ay = 0.0f, bx = 0.0f, by = 0.0f;
    #pragma unroll
    for (int m = 0; m < 32; m++) {
      float4 ta = ta_s[m];
      c32 pu = pu_s[m];
      float dxx = zx - ta.x;
      float dy1 = zy - ta.y;
      float dy2 = zy + ta.y;
      float xx  = dxx*dxx;
      float n1  = fmaf(dy1, dy1, xx);
      float n2  = fmaf(dy2, dy2, xx);
      float ip  = frcp(n1*n2);
      float i1  = n2*ip, i2 = n1*ip;
      float glx = dxx*i1, gly = -dy1*i1;      // 1/(z - d)
      float ghx = dxx*i2, ghy = -dy2*i2;      // 1/(z - conj d)
      float sx = glx + ghx, sy = gly + ghy;
      float dxg = glx - ghx, dyg = gly - ghy;
      fsx[m] = sx; fsy[m] = sy; fdx[m] = dxg; fdy[m] = dyg;
      ax = fmaf(ta.z, sx, fmaf(-ta.w, dyg, ax));
      ay = fmaf(ta.z, sy, fmaf( ta.w, dxg, ay));
      bx = fmaf(pu.x, sx, fmaf(-pu.y, dyg, bx));
      by = fmaf(pu.x, sy, fmaf( pu.y, dxg, by));
    }
    // q = z a/(1+b)
    float denx = 1.0f + bx, deny = by;
    float idn = frcp(fmaf(denx, denx, deny*deny));
    float tx = (ax*denx + ay*deny)*idn;
    float ty = (ay*denx - ax*deny)*idn;
    float qx = zx*tx - zy*ty;
    float qy = zx*ty + zy*tx;
    if (j == 0) { qx *= 0.5f; qy *= 0.5f; }   // self-conj node z=1
    #pragma unroll
    for (int m = 0; m < 32; m++) {
      sAx[m] = fmaf(qx, fsx[m], fmaf(-qy, fsy[m], sAx[m]));
      sAy[m] = fmaf(qx, fdy[m], fmaf( qy, fdx[m], sAy[m]));
    }
  }

  // ---- 6-level in-register wave butterfly: lane l ends with component l ----
  float arr[64];
  #pragma unroll
  for (int m = 0; m < 32; m++) { arr[2*m] = sAx[m]; arr[2*m+1] = sAy[m]; }
  const int lane = tid & 63;
  #pragma unroll
  for (int lv = 0; lv < 6; lv++) {
    const int p = 32 >> lv;
    const int half = 32 >> lv;
    bool hi = (lane & p) != 0;
    #pragma unroll
    for (int i = 0; i < half; i++) {
      float keep = hi ? arr[i + half] : arr[i];
      float send = hi ? arr[i] : arr[i + half];
      arr[i] = keep + __shfl_xor(send, p, 64);
    }
  }
  red[(tid >> 6)*64 + lane] = arr[0];
  __syncthreads();

  if (tid < 64) {
    float t = 0.0f;
    #pragma unroll
    for (int w = 0; w < 8; w++) t += red[w*64 + tid];
    Sws[bid*64 + tid] = t;    // layout: [h][half][component 0..63]
  }
}

// ---------------- K2: combine + Cauchy/Woodbury + irfft ----------------
__global__ __launch_bounds__(1024, 4)
void ssk_B(const float* __restrict__ log_dt, const float* __restrict__ invwr,
           const float* __restrict__ wim, const float* __restrict__ Pin,
           const float* __restrict__ Bin, const float* __restrict__ Cin,
           const float* __restrict__ Sws, c32* __restrict__ out)
{
  __shared__ __align__(16) c32 Xs[4098];   // spectrum / FFT ping
  __shared__ __align__(16) c32 Zs[4096];   // packed seq / FFT pong
  __shared__ c32 wdt_s[NN];
  __shared__ c32 vs[4][NN];
  const int h = blockIdx.x;
  const int tid = threadIdx.x;

  // ---- per-head algebra redo + combine (wave 0) ----
  if (tid < 64) {
    const int n = tid & 31;
    const bool cj = tid >= 32;
    const float dt = expf(log_dt[h]);
    float wr = -expf(invwr[h*NN + n]);
    float wi = wim[h*NN + n];
    if (cj) wi = -wi;
    const float tdt = 2.0f / dt;
    float dr = tdt - wr, di = -wi;
    float invd = 1.0f / (dr*dr + di*di);
    c32 D = make_float2(dr*invd, -di*invd);
    c32 E = make_float2(tdt + wr, wi);
    c32 Pf = make_float2(Pin[(h*NN+n)*2], Pin[(h*NN+n)*2+1]);
    if (cj) Pf.y = -Pf.y;
    c32 Cf = make_float2(Cin[(h*NN+n)*2], Cin[(h*NN+n)*2+1]);
    if (cj) Cf.y = -Cf.y;
    float rm = (Pf.x*Pf.x + Pf.y*Pf.y) * D.x;
    #pragma unroll
    for (int off = 32; off >= 1; off >>= 1) rm += __shfl_xor(rm, off, 64);
    rm += 1.0f;
    c32 Rc = cmul(cconjf(Pf), D);
    float invrm = 1.0f / rm;
    Rc.x *= invrm; Rc.y *= invrm;
    c32 RP = cmul(Rc, Pf);
    #pragma unroll
    for (int off = 32; off >= 1; off >>= 1) {
      RP.x += __shfl_xor(RP.x, off, 64);
      RP.y += __shfl_xor(RP.y, off, 64);
    }
    c32 Q2 = cconjf(Pf);
    c32 s  = csub(cmul(Rc, E), cmul(RP, Q2));
    c32 u  = cadd(Q2, s);
    c32 dd = cmul(D, E);
    c32 pp = cmul(D, Pf);
    c32 pc = cmul(pp, Cf);
    c32 pu = cmul(pp, u);

    // z = -1 node: g = conj(-1-d)/|.|^2 ; a,b real (conj-pair fold)
    float dxxn = -1.0f - dd.x;
    float nn1 = fmaf(dxxn, dxxn, dd.y*dd.y);
    float ii = frcp(nn1);
    float glxn = dxxn*ii, glyn = dd.y*ii;
    float aterm = 2.0f*(pc.x*glxn - pc.y*glyn);
    float bterm = 2.0f*(pu.x*glxn - pu.y*glyn);
    #pragma unroll
    for (int off = 16; off >= 1; off >>= 1) {
      aterm += __shfl_xor(aterm, off, 64);
      bterm += __shfl_xor(bterm, off, 64);
    }

    if (tid < 32) {
      const int m = tid;
      // exact diagonal part d^8192
      c32 dL = dd;
      #pragma unroll
      for (int i2 = 0; i2 < 13; i2++) dL = cmul(dL, dL);
      // total S: both halves + z=-1 node (q real, half weight)
      c32 S;
      S.x = Sws[h*128 + 2*m]     + Sws[h*128 + 64 + 2*m];
      S.y = Sws[h*128 + 2*m + 1] + Sws[h*128 + 64 + 2*m + 1];
      float qn = -aterm * frcp(1.0f + bterm) * 0.5f;
      S.x += qn * 2.0f * glxn;
      S.y += qn * 2.0f * glyn;
      // C~ = C - (C dL - u S / 8192)
      c32 y = cmul(Cf, dL);
      c32 uS = cmul(u, S);
      y.x -= uS.x * (1.0f/8192.0f);
      y.y -= uS.y * (1.0f/8192.0f);
      c32 Ct = csub(Cf, y);
      // stage-B vectors
      c32 Bc = make_float2(Bin[(h*NN+m)*2], Bin[(h*NN+m)*2+1]);
      c32 Qc = cconjf(Pf);    // lane<32: Pf unconjugated
      c32 v00 = cmul(Bc, Ct), v01 = cmul(Bc, Qc), v10 = cmul(Pf, Ct), v11 = cmul(Pf, Qc);
      vs[0][m] = make_float2(v00.x*dt, v00.y*dt);
      vs[1][m] = make_float2(v01.x*dt, v01.y*dt);
      vs[2][m] = make_float2(v10.x*dt, v10.y*dt);
      vs[3][m] = make_float2(v11.x*dt, v11.y*dt);
      wdt_s[m] = make_float2(wr*dt, wi*dt);
      // Nyquist X[4096] = sum Re(v00*dt)
      float s00 = v00.x * dt;
      #pragma unroll
      for (int off = 16; off >= 1; off >>= 1) s00 += __shfl_xor(s00, off, 64);
      if (m == 0) Xs[MF] = make_float2(s00, 0.0f);
    }
  }
  __syncthreads();

  // ---- Cauchy at z_j = 2i tan(pi j/L), 4 nodes/thread ----
  {
    float Tq[4], t2[4];
    c32 a00[4], a01[4], a10[4], a11[4];
    #pragma unroll
    for (int q = 0; q < 4; q++) {
      int j = tid + (q << 10);
      float rev = (float)j * (1.0f/16384.0f);
      float sn = __builtin_amdgcn_sinf(rev);
      float cs = __builtin_amdgcn_cosf(rev);
      float T = sn * frcp(cs);
      Tq[q] = T; t2[q] = 2.0f*T;
      a00[q] = make_float2(0,0); a01[q] = make_float2(0,0);
      a10[q] = make_float2(0,0); a11[q] = make_float2(0,0);
    }
    #pragma unroll 2
    for (int n = 0; n < NN; n++) {
      c32 w = wdt_s[n];
      float nr  = -w.x;
      float nr2 = nr*nr;
      float wy  = w.y;
      c32 v0 = vs[0][n], v1 = vs[1][n], v2 = vs[2][n], v3 = vs[3][n];
      #pragma unroll
      for (int q = 0; q < 4; q++) {
        float d1i = t2[q] - wy;
        float d2i = t2[q] + wy;
        float n1 = fmaf(d1i, d1i, nr2);
        float n2 = fmaf(d2i, d2i, nr2);
        float ip = frcp(n1*n2);
        float inv1 = n2*ip, inv2 = n1*ip;
        float c1x = nr*inv1, c1y = -d1i*inv1;
        float c2x = nr*inv2, c2y = -d2i*inv2;
        float sx = c1x + c2x, dxx = c1x - c2x;
        float sy = c1y + c2y, dyy = c1y - c2y;
        a00[q].x = fmaf(v0.x, sx, fmaf(-v0.y, dyy, a00[q].x));
        a00[q].y = fmaf(v0.x, sy, fmaf( v0.y, dxx, a00[q].y));
        a01[q].x = fmaf(v1.x, sx, fmaf(-v1.y, dyy, a01[q].x));
        a01[q].y = fmaf(v1.x, sy, fmaf( v1.y, dxx, a01[q].y));
        a10[q].x = fmaf(v2.x, sx, fmaf(-v2.y, dyy, a10[q].x));
        a10[q].y = fmaf(v2.x, sy, fmaf( v2.y, dxx, a10[q].y));
        a11[q].x = fmaf(v3.x, sx, fmaf(-v3.y, dyy, a11[q].x));
        a11[q].y = fmaf(v3.x, sy, fmaf( v3.y, dxx, a11[q].y));
      }
    }
    #pragma unroll
    for (int q = 0; q < 4; q++) {
      float denx = 1.0f + a11[q].x, deny = a11[q].y;
      float idn = frcp(fmaf(denx, denx, deny*deny));
      c32 invden = make_float2(denx*idn, -deny*idn);
      c32 kf = csub(a00[q], cmul(cmul(a01[q], a10[q]), invden));
      float T = Tq[q];
      Xs[tid + (q << 10)] = make_float2(kf.x - T*kf.y, kf.y + T*kf.x);  // *(1+iT)
    }
  }
  __syncthreads();

  // ---- real-irfft packing: Z[k] = (E[k] + i*O[k]) / MF ----
  const float invM = 1.0f / (float)MF;
  #pragma unroll
  for (int qq = 0; qq < 4; qq++) {
    int k = tid + (qq << 10);
    c32 Xk = Xs[k];
    c32 Xm = Xs[MF - k];
    float Ex = 0.5f*(Xk.x + Xm.x), Ey = 0.5f*(Xk.y - Xm.y);
    float Ox = 0.5f*(Xk.x - Xm.x), Oy = 0.5f*(Xk.y + Xm.y);
    float rev = (float)k * (1.0f/8192.0f);
    float cs = __builtin_amdgcn_cosf(rev);
    float sn = __builtin_amdgcn_sinf(rev);
    float Orx = Ox*cs - Oy*sn;
    float Ory = Ox*sn + Oy*cs;
    Zs[k] = make_float2((Ex - Ory)*invM, (Ey + Orx)*invM);
  }
  __syncthreads();

  // ---- 6-stage radix-4 Stockham inverse FFT (twiddle sign +) ----
  c32* srcf = Zs;
  c32* dstf = Xs;
  int sstride = 1;
  #pragma unroll
  for (int st = 0; st < 6; st++) {
    int jm = tid & ~(sstride - 1);
    float rev = (float)jm * (1.0f/4096.0f);
    float sn = __builtin_amdgcn_sinf(rev);
    float cs = __builtin_amdgcn_cosf(rev);
    c32 w1 = make_float2(cs, sn);
    c32 w2 = cmul(w1, w1);
    c32 w3 = cmul(w2, w1);
    c32 a = srcf[tid];
    c32 b = srcf[tid + 1024];
    c32 c = srcf[tid + 2048];
    c32 d = srcf[tid + 3072];
    c32 apc = cadd(a, c), amc = csub(a, c);
    c32 bpd = cadd(b, d), bmd = csub(b, d);
    int wb = tid + 3*jm;
    dstf[wb] = cadd(apc, bpd);
    dstf[wb + sstride]   = cmul(w1, make_float2(amc.x - bmd.y, amc.y + bmd.x));
    dstf[wb + 2*sstride] = cmul(w2, csub(apc, bpd));
    dstf[wb + 3*sstride] = cmul(w3, make_float2(amc.x + bmd.y, amc.y - bmd.x));
    __syncthreads();
    c32* t = srcf; srcf = dstf; dstf = t;
    sstride <<= 2;
  }

  // even stage count -> result in Zs (= srcf); z[m] = (x[2m], x[2m+1])
  {
    float4* o4 = (float4*)(out + (size_t)h*MF);
    const float4* s4 = (const float4*)srcf;
    o4[tid] = s4[tid];
    o4[tid + 1024] = s4[tid + 1024];
  }
}

extern "C" void kernel_launch(void* const* d_in, const int* in_sizes, int n_in,
                              void* d_out, int out_size, void* d_ws, size_t ws_size,
                              hipStream_t stream) {
  const float* log_dt = (const float*)d_in[0];
  const float* invwr  = (const float*)d_in[1];
  const float* wimag  = (const float*)d_in[2];
  const float* P      = (const float*)d_in[3];
  const float* B      = (const float*)d_in[4];
  const float* C      = (const float*)d_in[5];
  float* Sws = (float*)d_ws;                 // 512 blocks * 64 floats = 128 KB
  c32*   out = (c32*)d_out;                  // (H,8192) fp32 = (H,4096) c32
  (void)in_sizes; (void)n_in; (void)out_size; (void)ws_size;

  ssk_S<<<2*HH, 512, 0, stream>>>(log_dt, invwr, wimag, P, C, Sws);
  ssk_B<<<HH, 1024, 0, stream>>>(log_dt, invwr, wimag, P, B, C, Sws, out);
}

// Round 9
// 72.890 us; speedup vs baseline: 4.1526x; 4.1526x over previous
//
#include <hip/hip_runtime.h>

// SSKernelNPLR, 2-kernel pipeline. H=256, N=32 (M=64 conj-extended), R=1, L=8192.
// K1 ssk_S (grid 512, 512 thr): register-fused contour with 4-lane node groups.
//    Lane l of each quad owns 8 state-pairs (m = (l&3)*8+k). Per node j:
//    8 G-folds -> 32 VGPRs + local (a,b); quad shfl_xor(1,2) reduce -> full
//    (a_j,b_j); q_j = z a/(1+b) (quad-redundant); S_m += q-fold into 16 VGPRs.
//    16 node-iters/thread. Reduce: masked wave butterfly (xor 4..32) -> LDS ->
//    64-thread cross-wave sum -> Sws (layout [h][half][2m+bit], same as r6).
// K2 ssk_B (grid 256, 1024 thr): per-head algebra redo + combine S halves +
//    z=-1 node -> C~ -> v-vectors; Cauchy at z_j = 2i tan(pi j/L) + Woodbury
//    + (1+iT); real-irfft packing; 6-stage radix-4 Stockham inverse FFT -> out.

#define HH 256
#define NN 32
#define MF 4096

typedef float2 c32;

__device__ __forceinline__ c32 cmul(c32 a, c32 b){ return make_float2(a.x*b.x - a.y*b.y, a.x*b.y + a.y*b.x); }
__device__ __forceinline__ c32 cadd(c32 a, c32 b){ return make_float2(a.x+b.x, a.y+b.y); }
__device__ __forceinline__ c32 csub(c32 a, c32 b){ return make_float2(a.x-b.x, a.y-b.y); }
__device__ __forceinline__ c32 cconjf(c32 a){ return make_float2(a.x, -a.y); }
__device__ __forceinline__ float frcp(float x){ return __builtin_amdgcn_rcpf(x); }

// ---------------- K1: register-fused contour (4-lane node groups) ----------
__global__ __launch_bounds__(512, 2)
void ssk_S(const float* __restrict__ log_dt, const float* __restrict__ invwr,
           const float* __restrict__ wim, const float* __restrict__ Pin,
           const float* __restrict__ Cin, float* __restrict__ Sws)
{
  __shared__ __align__(16) float4 ta_s[32];   // (d.x, d.y, pc.x, pc.y)
  __shared__ c32 pu_s[32];
  __shared__ float red[8*4*16];               // [wave][sub][16]
  const int bid = blockIdx.x;
  const int h = bid >> 1;
  const int base = (bid & 1) << 11;           // 0 or 2048
  const int tid = threadIdx.x;

  // ---- A1: per-head algebra (wave 0; m = tid, conj half for m>=32) ----
  if (tid < 64) {
    const int n = tid & 31;
    const bool cj = tid >= 32;
    const float dt = expf(log_dt[h]);
    float wr = -expf(invwr[h*NN + n]);
    float wi = wim[h*NN + n];
    if (cj) wi = -wi;
    const float tdt = 2.0f / dt;
    float dr = tdt - wr, di = -wi;
    float invd = 1.0f / (dr*dr + di*di);
    c32 D = make_float2(dr*invd, -di*invd);   // 1/(2/dt - w)
    c32 E = make_float2(tdt + wr, wi);        // 2/dt + w
    c32 Pf = make_float2(Pin[(h*NN+n)*2], Pin[(h*NN+n)*2+1]);
    if (cj) Pf.y = -Pf.y;
    c32 Cf = make_float2(Cin[(h*NN+n)*2], Cin[(h*NN+n)*2+1]);
    if (cj) Cf.y = -Cf.y;
    float rm = (Pf.x*Pf.x + Pf.y*Pf.y) * D.x; // Rm = 1 + sum |Pf|^2 Re(D)
    #pragma unroll
    for (int off = 32; off >= 1; off >>= 1) rm += __shfl_xor(rm, off, 64);
    rm += 1.0f;
    c32 Rc = cmul(cconjf(Pf), D);
    float invrm = 1.0f / rm;
    Rc.x *= invrm; Rc.y *= invrm;
    c32 RP = cmul(Rc, Pf);
    #pragma unroll
    for (int off = 32; off >= 1; off >>= 1) {
      RP.x += __shfl_xor(RP.x, off, 64);
      RP.y += __shfl_xor(RP.y, off, 64);
    }
    c32 Q2 = cconjf(Pf);
    c32 s  = csub(cmul(Rc, E), cmul(RP, Q2));
    c32 u  = cadd(Q2, s);                     // dA = diag(dd) - pp u^T
    c32 dd = cmul(D, E);
    c32 pp = cmul(D, Pf);
    c32 pc = cmul(pp, Cf);
    c32 pu = cmul(pp, u);
    if (tid < 32) {
      ta_s[tid] = make_float4(dd.x, dd.y, pc.x, pc.y);
      pu_s[tid] = pu;
    }
  }
  __syncthreads();

  const int sub = tid & 3;                    // 8-state slice
  const int grp = tid >> 2;                   // node slot 0..127

  // per-thread param registers for states m = sub*8 + k
  float pdx[8], pdy[8], pcx[8], pcy[8], pux[8], puy[8];
  #pragma unroll
  for (int k = 0; k < 8; k++) {
    float4 ta = ta_s[sub*8 + k];
    c32 pu = pu_s[sub*8 + k];
    pdx[k] = ta.x; pdy[k] = ta.y; pcx[k] = ta.z; pcy[k] = ta.w;
    pux[k] = pu.x; puy[k] = pu.y;
  }

  float ssx[8], ssy[8];
  #pragma unroll
  for (int k = 0; k < 8; k++) { ssx[k] = 0.0f; ssy[k] = 0.0f; }

  for (int it = 0; it < 16; it++) {
    const int j = base + (it << 7) + grp;     // node index 0..4095
    float rev = (float)j * (1.0f/8192.0f);
    float zx = __builtin_amdgcn_cosf(rev);
    float zy = __builtin_amdgcn_sinf(rev);

    float fsx[8], fsy[8], fdx[8], fdy[8];
    float ax = 0.0f, ay = 0.0f, bx = 0.0f, by = 0.0f;
    #pragma unroll
    for (int k = 0; k < 8; k++) {
      float dxx = zx - pdx[k];
      float dy1 = zy - pdy[k];
      float dy2 = zy + pdy[k];
      float xx  = dxx*dxx;
      float n1  = fmaf(dy1, dy1, xx);
      float n2  = fmaf(dy2, dy2, xx);
      float ip  = frcp(n1*n2);
      float i1  = n2*ip, i2 = n1*ip;
      float glx = dxx*i1, gly = -dy1*i1;      // 1/(z - d)
      float ghx = dxx*i2, ghy = -dy2*i2;      // 1/(z - conj d)
      float sx = glx + ghx, sy = gly + ghy;
      float dxg = glx - ghx, dyg = gly - ghy;
      fsx[k] = sx; fsy[k] = sy; fdx[k] = dxg; fdy[k] = dyg;
      ax = fmaf(pcx[k], sx, fmaf(-pcy[k], dyg, ax));
      ay = fmaf(pcx[k], sy, fmaf( pcy[k], dxg, ay));
      bx = fmaf(pux[k], sx, fmaf(-puy[k], dyg, bx));
      by = fmaf(pux[k], sy, fmaf( puy[k], dxg, by));
    }
    // quad reduce: lanes of the 4-group hold disjoint state slices
    ax += __shfl_xor(ax, 1, 64); ax += __shfl_xor(ax, 2, 64);
    ay += __shfl_xor(ay, 1, 64); ay += __shfl_xor(ay, 2, 64);
    bx += __shfl_xor(bx, 1, 64); bx += __shfl_xor(bx, 2, 64);
    by += __shfl_xor(by, 1, 64); by += __shfl_xor(by, 2, 64);
    // q = z a/(1+b)  (quad-redundant)
    float denx = 1.0f + bx, deny = by;
    float idn = frcp(fmaf(denx, denx, deny*deny));
    float tx = (ax*denx + ay*deny)*idn;
    float ty = (ay*denx - ax*deny)*idn;
    float qx = zx*tx - zy*ty;
    float qy = zx*ty + zy*tx;
    if (j == 0) { qx *= 0.5f; qy *= 0.5f; }   // self-conj node z=1
    #pragma unroll
    for (int k = 0; k < 8; k++) {
      ssx[k] = fmaf(qx, fsx[k], fmaf(-qy, fsy[k], ssx[k]));
      ssy[k] = fmaf(qx, fdy[k], fmaf( qy, fdx[k], ssy[k]));
    }
  }

  // ---- masked wave butterfly: combine lanes with the same sub ----
  #pragma unroll
  for (int off = 4; off <= 32; off <<= 1) {
    #pragma unroll
    for (int k = 0; k < 8; k++) {
      ssx[k] += __shfl_xor(ssx[k], off, 64);
      ssy[k] += __shfl_xor(ssy[k], off, 64);
    }
  }
  const int lane = tid & 63;
  const int wv = tid >> 6;
  if (lane < 4) {
    #pragma unroll
    for (int k = 0; k < 8; k++) {
      red[(wv*4 + lane)*16 + 2*k]     = ssx[k];
      red[(wv*4 + lane)*16 + 2*k + 1] = ssy[k];
    }
  }
  __syncthreads();

  // cross-wave sum; component c = 2m + bit  (c = (m>>3)*16 + (m&7)*2 + bit)
  if (tid < 64) {
    float t = 0.0f;
    #pragma unroll
    for (int w = 0; w < 8; w++) t += red[(w*4 + (tid >> 4))*16 + (tid & 15)];
    Sws[bid*64 + tid] = t;    // layout: [h][half][2m+bit]
  }
}

// ---------------- K2: combine + Cauchy/Woodbury + irfft (r6, verified) -----
__global__ __launch_bounds__(1024, 4)
void ssk_B(const float* __restrict__ log_dt, const float* __restrict__ invwr,
           const float* __restrict__ wim, const float* __restrict__ Pin,
           const float* __restrict__ Bin, const float* __restrict__ Cin,
           const float* __restrict__ Sws, c32* __restrict__ out)
{
  __shared__ __align__(16) c32 Xs[4098];   // spectrum / FFT ping
  __shared__ __align__(16) c32 Zs[4096];   // packed seq / FFT pong
  __shared__ c32 wdt_s[NN];
  __shared__ c32 vs[4][NN];
  const int h = blockIdx.x;
  const int tid = threadIdx.x;

  // ---- per-head algebra redo + combine (wave 0) ----
  if (tid < 64) {
    const int n = tid & 31;
    const bool cj = tid >= 32;
    const float dt = expf(log_dt[h]);
    float wr = -expf(invwr[h*NN + n]);
    float wi = wim[h*NN + n];
    if (cj) wi = -wi;
    const float tdt = 2.0f / dt;
    float dr = tdt - wr, di = -wi;
    float invd = 1.0f / (dr*dr + di*di);
    c32 D = make_float2(dr*invd, -di*invd);
    c32 E = make_float2(tdt + wr, wi);
    c32 Pf = make_float2(Pin[(h*NN+n)*2], Pin[(h*NN+n)*2+1]);
    if (cj) Pf.y = -Pf.y;
    c32 Cf = make_float2(Cin[(h*NN+n)*2], Cin[(h*NN+n)*2+1]);
    if (cj) Cf.y = -Cf.y;
    float rm = (Pf.x*Pf.x + Pf.y*Pf.y) * D.x;
    #pragma unroll
    for (int off = 32; off >= 1; off >>= 1) rm += __shfl_xor(rm, off, 64);
    rm += 1.0f;
    c32 Rc = cmul(cconjf(Pf), D);
    float invrm = 1.0f / rm;
    Rc.x *= invrm; Rc.y *= invrm;
    c32 RP = cmul(Rc, Pf);
    #pragma unroll
    for (int off = 32; off >= 1; off >>= 1) {
      RP.x += __shfl_xor(RP.x, off, 64);
      RP.y += __shfl_xor(RP.y, off, 64);
    }
    c32 Q2 = cconjf(Pf);
    c32 s  = csub(cmul(Rc, E), cmul(RP, Q2));
    c32 u  = cadd(Q2, s);
    c32 dd = cmul(D, E);
    c32 pp = cmul(D, Pf);
    c32 pc = cmul(pp, Cf);
    c32 pu = cmul(pp, u);

    // z = -1 node: g = conj(-1-d)/|.|^2 ; a,b real (conj-pair fold)
    float dxxn = -1.0f - dd.x;
    float nn1 = fmaf(dxxn, dxxn, dd.y*dd.y);
    float ii = frcp(nn1);
    float glxn = dxxn*ii, glyn = dd.y*ii;
    float aterm = 2.0f*(pc.x*glxn - pc.y*glyn);
    float bterm = 2.0f*(pu.x*glxn - pu.y*glyn);
    #pragma unroll
    for (int off = 16; off >= 1; off >>= 1) {
      aterm += __shfl_xor(aterm, off, 64);
      bterm += __shfl_xor(bterm, off, 64);
    }

    if (tid < 32) {
      const int m = tid;
      // exact diagonal part d^8192
      c32 dL = dd;
      #pragma unroll
      for (int i2 = 0; i2 < 13; i2++) dL = cmul(dL, dL);
      // total S: both halves + z=-1 node (q real, half weight)
      c32 S;
      S.x = Sws[h*128 + 2*m]     + Sws[h*128 + 64 + 2*m];
      S.y = Sws[h*128 + 2*m + 1] + Sws[h*128 + 64 + 2*m + 1];
      float qn = -aterm * frcp(1.0f + bterm) * 0.5f;
      S.x += qn * 2.0f * glxn;
      S.y += qn * 2.0f * glyn;
      // C~ = C - (C dL - u S / 8192)
      c32 y = cmul(Cf, dL);
      c32 uS = cmul(u, S);
      y.x -= uS.x * (1.0f/8192.0f);
      y.y -= uS.y * (1.0f/8192.0f);
      c32 Ct = csub(Cf, y);
      // stage-B vectors
      c32 Bc = make_float2(Bin[(h*NN+m)*2], Bin[(h*NN+m)*2+1]);
      c32 Qc = cconjf(Pf);    // lane<32: Pf unconjugated
      c32 v00 = cmul(Bc, Ct), v01 = cmul(Bc, Qc), v10 = cmul(Pf, Ct), v11 = cmul(Pf, Qc);
      vs[0][m] = make_float2(v00.x*dt, v00.y*dt);
      vs[1][m] = make_float2(v01.x*dt, v01.y*dt);
      vs[2][m] = make_float2(v10.x*dt, v10.y*dt);
      vs[3][m] = make_float2(v11.x*dt, v11.y*dt);
      wdt_s[m] = make_float2(wr*dt, wi*dt);
      // Nyquist X[4096] = sum Re(v00*dt)
      float s00 = v00.x * dt;
      #pragma unroll
      for (int off = 16; off >= 1; off >>= 1) s00 += __shfl_xor(s00, off, 64);
      if (m == 0) Xs[MF] = make_float2(s00, 0.0f);
    }
  }
  __syncthreads();

  // ---- Cauchy at z_j = 2i tan(pi j/L), 4 nodes/thread ----
  {
    float Tq[4], t2[4];
    c32 a00[4], a01[4], a10[4], a11[4];
    #pragma unroll
    for (int q = 0; q < 4; q++) {
      int j = tid + (q << 10);
      float rev = (float)j * (1.0f/16384.0f);
      float sn = __builtin_amdgcn_sinf(rev);
      float cs = __builtin_amdgcn_cosf(rev);
      float T = sn * frcp(cs);
      Tq[q] = T; t2[q] = 2.0f*T;
      a00[q] = make_float2(0,0); a01[q] = make_float2(0,0);
      a10[q] = make_float2(0,0); a11[q] = make_float2(0,0);
    }
    #pragma unroll 2
    for (int n = 0; n < NN; n++) {
      c32 w = wdt_s[n];
      float nr  = -w.x;
      float nr2 = nr*nr;
      float wy  = w.y;
      c32 v0 = vs[0][n], v1 = vs[1][n], v2 = vs[2][n], v3 = vs[3][n];
      #pragma unroll
      for (int q = 0; q < 4; q++) {
        float d1i = t2[q] - wy;
        float d2i = t2[q] + wy;
        float n1 = fmaf(d1i, d1i, nr2);
        float n2 = fmaf(d2i, d2i, nr2);
        float ip = frcp(n1*n2);
        float inv1 = n2*ip, inv2 = n1*ip;
        float c1x = nr*inv1, c1y = -d1i*inv1;
        float c2x = nr*inv2, c2y = -d2i*inv2;
        float sx = c1x + c2x, dxx = c1x - c2x;
        float sy = c1y + c2y, dyy = c1y - c2y;
        a00[q].x = fmaf(v0.x, sx, fmaf(-v0.y, dyy, a00[q].x));
        a00[q].y = fmaf(v0.x, sy, fmaf( v0.y, dxx, a00[q].y));
        a01[q].x = fmaf(v1.x, sx, fmaf(-v1.y, dyy, a01[q].x));
        a01[q].y = fmaf(v1.x, sy, fmaf( v1.y, dxx, a01[q].y));
        a10[q].x = fmaf(v2.x, sx, fmaf(-v2.y, dyy, a10[q].x));
        a10[q].y = fmaf(v2.x, sy, fmaf( v2.y, dxx, a10[q].y));
        a11[q].x = fmaf(v3.x, sx, fmaf(-v3.y, dyy, a11[q].x));
        a11[q].y = fmaf(v3.x, sy, fmaf( v3.y, dxx, a11[q].y));
      }
    }
    #pragma unroll
    for (int q = 0; q < 4; q++) {
      float denx = 1.0f + a11[q].x, deny = a11[q].y;
      float idn = frcp(fmaf(denx, denx, deny*deny));
      c32 invden = make_float2(denx*idn, -deny*idn);
      c32 kf = csub(a00[q], cmul(cmul(a01[q], a10[q]), invden));
      float T = Tq[q];
      Xs[tid + (q << 10)] = make_float2(kf.x - T*kf.y, kf.y + T*kf.x);  // *(1+iT)
    }
  }
  __syncthreads();

  // ---- real-irfft packing: Z[k] = (E[k] + i*O[k]) / MF ----
  const float invM = 1.0f / (float)MF;
  #pragma unroll
  for (int qq = 0; qq < 4; qq++) {
    int k = tid + (qq << 10);
    c32 Xk = Xs[k];
    c32 Xm = Xs[MF - k];
    float Ex = 0.5f*(Xk.x + Xm.x), Ey = 0.5f*(Xk.y - Xm.y);
    float Ox = 0.5f*(Xk.x - Xm.x), Oy = 0.5f*(Xk.y + Xm.y);
    float rev = (float)k * (1.0f/8192.0f);
    float cs = __builtin_amdgcn_cosf(rev);
    float sn = __builtin_amdgcn_sinf(rev);
    float Orx = Ox*cs - Oy*sn;
    float Ory = Ox*sn + Oy*cs;
    Zs[k] = make_float2((Ex - Ory)*invM, (Ey + Orx)*invM);
  }
  __syncthreads();

  // ---- 6-stage radix-4 Stockham inverse FFT (twiddle sign +) ----
  c32* srcf = Zs;
  c32* dstf = Xs;
  int sstride = 1;
  #pragma unroll
  for (int st = 0; st < 6; st++) {
    int jm = tid & ~(sstride - 1);
    float rev = (float)jm * (1.0f/4096.0f);
    float sn = __builtin_amdgcn_sinf(rev);
    float cs = __builtin_amdgcn_cosf(rev);
    c32 w1 = make_float2(cs, sn);
    c32 w2 = cmul(w1, w1);
    c32 w3 = cmul(w2, w1);
    c32 a = srcf[tid];
    c32 b = srcf[tid + 1024];
    c32 c = srcf[tid + 2048];
    c32 d = srcf[tid + 3072];
    c32 apc = cadd(a, c), amc = csub(a, c);
    c32 bpd = cadd(b, d), bmd = csub(b, d);
    int wb = tid + 3*jm;
    dstf[wb] = cadd(apc, bpd);
    dstf[wb + sstride]   = cmul(w1, make_float2(amc.x - bmd.y, amc.y + bmd.x));
    dstf[wb + 2*sstride] = cmul(w2, csub(apc, bpd));
    dstf[wb + 3*sstride] = cmul(w3, make_float2(amc.x + bmd.y, amc.y - bmd.x));
    __syncthreads();
    c32* t = srcf; srcf = dstf; dstf = t;
    sstride <<= 2;
  }

  // even stage count -> result in Zs (= srcf); z[m] = (x[2m], x[2m+1])
  {
    float4* o4 = (float4*)(out + (size_t)h*MF);
    const float4* s4 = (const float4*)srcf;
    o4[tid] = s4[tid];
    o4[tid + 1024] = s4[tid + 1024];
  }
}

extern "C" void kernel_launch(void* const* d_in, const int* in_sizes, int n_in,
                              void* d_out, int out_size, void* d_ws, size_t ws_size,
                              hipStream_t stream) {
  const float* log_dt = (const float*)d_in[0];
  const float* invwr  = (const float*)d_in[1];
  const float* wimag  = (const float*)d_in[2];
  const float* P      = (const float*)d_in[3];
  const float* B      = (const float*)d_in[4];
  const float* C      = (const float*)d_in[5];
  float* Sws = (float*)d_ws;                 // 512 blocks * 64 floats = 128 KB
  c32*   out = (c32*)d_out;                  // (H,8192) fp32 = (H,4096) c32
  (void)in_sizes; (void)n_in; (void)out_size; (void)ws_size;

  ssk_S<<<2*HH, 512, 0, stream>>>(log_dt, invwr, wimag, P, C, Sws);
  ssk_B<<<HH, 1024, 0, stream>>>(log_dt, invwr, wimag, P, B, C, Sws, out);
}